// Round 20
// baseline (137.428 us; speedup 1.0000x reference)
//
#include <hip/hip_runtime.h>

// Conv2d 3x3 VALID (NCHW/OIHW, fp32), fp16 MFMA, v14 "256-sp tile".
// prep_x: X -> X16t[n][h][w][c] fp16 (v12-verified). main: 256sp x 128cout
// tile (grid 1513, tail-guarded), 8 waves = 2 cout-halves x 4 sp-quarters,
// wave = 64x64 -> acc[2][2]; per kk 2 B-reads feed 4 MFMAs (0.5 rd/MFMA).
// v13 row-granular lean staging, SLOTS=264 (wx_max=261+2 proven), 3 rounds,
// 4 barriers. Per-output: blocks/barriers/A-L2/prologue all HALVED.
// Accumulation order s=0..8 unchanged -> bit-identical output.

typedef __attribute__((ext_vector_type(8)))  _Float16 f16x8;
typedef __attribute__((ext_vector_type(16))) float    f32x16;

typedef __attribute__((address_space(3))) uint       lds_u32;
typedef __attribute__((address_space(1))) const uint glb_u32;

constexpr int C_IN = 64, H = 112, W = 112;
constexpr int COUT = 128, OH = 110, OW = 110;
constexpr int NIMG = 32;
constexpr int KTOT = C_IN * 9;            // 576
constexpr int OSP  = OH * OW;             // 12100
constexpr int SPTOT = NIMG * OSP;         // 387200
constexpr int IMG_STRIDE = C_IN * H * W;
constexpr int CH_STRIDE  = H * W;         // 12544 (slots per image in X16t)
constexpr int XROW = W * C_IN;            // 7168 fp16 per X16t row
constexpr int TILE = 256;
constexpr int NWGM = (SPTOT + TILE - 1) / TILE;   // 1513 (tail block half-dead)
constexpr int SLOTS = 264;                // staged w-slots per kernel row
constexpr size_t A16_BYTES = (size_t)KTOT * COUT * 2;

__device__ __forceinline__ uint pkrtz_u32(float lo, float hi) {
    union { __fp16 __attribute__((ext_vector_type(2))) h; uint u; } c;
    c.h = __builtin_amdgcn_cvt_pkrtz(lo, hi);
    return c.u;
}

// A16[((s*8+o)*COUT + cout)*8 + j] = (f16)Kw[cout][(o*8+j)*9 + s]  (v4-verified)
__global__ void prep_a(const float* __restrict__ Kw, _Float16* __restrict__ A16) {
    int idx = blockIdx.x * 256 + threadIdx.x;
    if (idx >= COUT * KTOT) return;
    int cout = idx / KTOT, k = idx - cout * KTOT;
    int c = k / 9, s = k - c * 9;
    int o = c >> 3, j = c & 7;
    A16[((size_t)(s * 8 + o) * COUT + cout) * 8 + j] = (_Float16)Kw[idx];
}

// X16t[n][h][w][c] = (f16)X[n][c][h][w]  (v12-verified, LDS transpose)
__global__ __launch_bounds__(256, 4)
void prep_x(const float* __restrict__ X, _Float16* __restrict__ X16t) {
    __shared__ _Float16 L[W * 72];
    const int t = threadIdx.x;
    const int n = blockIdx.x / H, h = blockIdx.x - n * H;
    const float* src = X + (size_t)n * IMG_STRIDE + (size_t)h * W;
    const int c = t >> 2, q = t & 3;
    const float* sc = src + (size_t)c * CH_STRIDE + q * 28;
#pragma unroll
    for (int v = 0; v < 7; v++) {
        float4 f = *reinterpret_cast<const float4*>(sc + v * 4);
        const int w0 = q * 28 + v * 4;
        L[(w0 + 0) * 72 + c] = (_Float16)f.x;
        L[(w0 + 1) * 72 + c] = (_Float16)f.y;
        L[(w0 + 2) * 72 + c] = (_Float16)f.z;
        L[(w0 + 3) * 72 + c] = (_Float16)f.w;
    }
    __syncthreads();
    _Float16* dst = X16t + ((size_t)n * H + h) * XROW;
#pragma unroll
    for (int r = 0; r < 4; r++) {
        const int u = r * 256 + t;
        if (u < 896) {
            const int w = u >> 3, sl = u & 7;
            *reinterpret_cast<f16x8*>(dst + (size_t)u * 8) =
                *reinterpret_cast<const f16x8*>(&L[w * 72 + sl * 8]);
        }
    }
}

__global__ __launch_bounds__(512, 4)
void conv_v14(const _Float16* __restrict__ X16t,
              const _Float16* __restrict__ A16,
              float* __restrict__ Out)
{
    __shared__ __align__(16) _Float16 Bs[2][SLOTS * 64];   // 2 x 33792 B

    const int t = threadIdx.x;
    const int lane = t & 63;
    const int wv   = t >> 6;

    // XCD-bijective block swizzle (m204); nwg=1513
    const int nwg = gridDim.x;
    const int q8 = nwg >> 3, r8 = nwg & 7;
    const int xcd = blockIdx.x & 7, idx8 = blockIdx.x >> 3;
    const int bid = (xcd < r8 ? xcd * (q8 + 1) : r8 * (q8 + 1) + (xcd - r8) * q8) + idx8;
    const int spBase = bid * TILE;

    const int n0  = spBase / OSP;
    const int r0  = spBase - n0 * OSP;
    const int oh0 = r0 / OW;
    const int ow0 = r0 - oh0 * OW;
    const int seg1len = (110 - oh0) * 112 - ow0;   // slots from image n0 (incl. halo)

    // ---- staging sources: units u = t, t+512, t+1024, t+1536, [t<64] 2048+t ----
    const _Float16 *sU0, *sU1, *sU2, *sU3, *sU4;
    {
        const _Float16* ss[5];
#pragma unroll
        for (int i = 0; i < 5; i++) {
            const int u  = (i < 4) ? (t + 512 * i) : (2048 + lane);
            const int ws = u >> 3, oct = u & 7;
            size_t lin;
            if (ws < seg1len) {
                lin = (size_t)n0 * CH_STRIDE + (size_t)(oh0 * 112 + ow0 + ws);
            } else {
                const int nn = (n0 < NIMG - 1) ? n0 + 1 : n0;  // clamp: pad never read
                lin = (size_t)nn * CH_STRIDE + (size_t)(ws - seg1len);
            }
            ss[i] = X16t + lin * 64 + ((oct ^ (ws & 7)) << 3);
        }
        sU0 = ss[0]; sU1 = ss[1]; sU2 = ss[2]; sU3 = ss[3]; sU4 = ss[4];
    }

    // ---- compute mapping: 8 waves = 2 cout-halves x 4 sp-quarters (64x64) ----
    const int wq2   = wv >> 2;          // cout half
    const int wsp   = wv & 3;           // sp quarter
    const int frow  = lane & 31;
    const int khalf = lane >> 5;
    const size_t arow0 = (size_t)(wq2 * 64 + frow) * 8;
    const size_t arow1 = (size_t)(wq2 * 64 + 32 + frow) * 8;

    // per-lane B slot indices for the wave's two sp rows (tail-clamped)
    int w0i, w1i;
    {
        int wx[2];
#pragma unroll
        for (int j = 0; j < 2; j++) {
            const int spg = spBase + wsp * 64 + j * 32 + frow;
            int v = 0;
            if (spg < SPTOT) {
                const int n  = spg / OSP;
                const int r  = spg - n * OSP;
                const int oh = r / OW, ow = r - oh * OW;
                v = (n == n0) ? (oh - oh0) * 112 + (ow - ow0)
                              : seg1len + oh * 112 + ow;
            }
            wx[j] = v;
        }
        w0i = wx[0]; w1i = wx[1];
    }

    f32x16 acc[2][2];
#pragma unroll
    for (int i = 0; i < 2; i++)
#pragma unroll
        for (int j = 0; j < 2; j++)
#pragma unroll
            for (int e = 0; e < 16; e++) acc[i][j][e] = 0.f;

    f16x8 a0[4], a1[4];

#define STAGE(R, B)                                                            \
    {                                                                          \
        __builtin_amdgcn_global_load_lds((const glb_u32*)(sU0 + (R) * XROW),   \
            (lds_u32*)(&Bs[B][(size_t)t * 8]), 16, 0, 0);                      \
        __builtin_amdgcn_global_load_lds((const glb_u32*)(sU1 + (R) * XROW),   \
            (lds_u32*)(&Bs[B][(size_t)(t + 512) * 8]), 16, 0, 0);              \
        __builtin_amdgcn_global_load_lds((const glb_u32*)(sU2 + (R) * XROW),   \
            (lds_u32*)(&Bs[B][(size_t)(t + 1024) * 8]), 16, 0, 0);             \
        __builtin_amdgcn_global_load_lds((const glb_u32*)(sU3 + (R) * XROW),   \
            (lds_u32*)(&Bs[B][(size_t)(t + 1536) * 8]), 16, 0, 0);             \
        if (t < 64)                                                            \
            __builtin_amdgcn_global_load_lds((const glb_u32*)(sU4 + (R) * XROW), \
                (lds_u32*)(&Bs[B][(size_t)(2048 + lane) * 8]), 16, 0, 0);      \
    }

#define ALOAD(S)                                                               \
    {                                                                          \
        _Pragma("unroll")                                                      \
        for (int kk = 0; kk < 4; kk++) {                                       \
            const size_t ab = (size_t)(((S) * 8 + kk * 2 + khalf) * COUT) * 8; \
            a0[kk] = *reinterpret_cast<const f16x8*>(&A16[ab + arow0]);        \
            a1[kk] = *reinterpret_cast<const f16x8*>(&A16[ab + arow1]);        \
        }                                                                      \
    }

#define MFMA_SH(KW, B)                                                         \
    {                                                                          \
        const int sa = w0i + (KW);                                             \
        const int sb = w1i + (KW);                                             \
        _Pragma("unroll")                                                      \
        for (int kk = 0; kk < 4; kk++) {                                       \
            const int oct = kk * 2 + khalf;                                    \
            f16x8 b0 = *reinterpret_cast<const f16x8*>(                        \
                &Bs[B][sa * 64 + ((oct ^ (sa & 7)) << 3)]);                    \
            f16x8 b1 = *reinterpret_cast<const f16x8*>(                        \
                &Bs[B][sb * 64 + ((oct ^ (sb & 7)) << 3)]);                    \
            acc[0][0] = __builtin_amdgcn_mfma_f32_32x32x16_f16(a0[kk], b0, acc[0][0], 0, 0, 0); \
            acc[0][1] = __builtin_amdgcn_mfma_f32_32x32x16_f16(a0[kk], b1, acc[0][1], 0, 0, 0); \
            acc[1][0] = __builtin_amdgcn_mfma_f32_32x32x16_f16(a1[kk], b0, acc[1][0], 0, 0, 0); \
            acc[1][1] = __builtin_amdgcn_mfma_f32_32x32x16_f16(a1[kk], b1, acc[1][1], 0, 0, 0); \
        }                                                                      \
    }

    // ---- prologue: row0 -> buf0 ----
    STAGE(0, 0);
    __syncthreads();

    // ---- R=0 (shifts 0,1,2 from buf0), stage row1 -> buf1 ----
    STAGE(1, 1);
    ALOAD(0); MFMA_SH(0, 0);
    ALOAD(1); MFMA_SH(1, 0);
    ALOAD(2); MFMA_SH(2, 0);
    __syncthreads();

    // ---- R=1 (shifts 3,4,5 from buf1), stage row2 -> buf0 ----
    STAGE(2, 0);
    ALOAD(3); MFMA_SH(0, 1);
    ALOAD(4); MFMA_SH(1, 1);
    ALOAD(5); MFMA_SH(2, 1);
    __syncthreads();

    // ---- R=2 (shifts 6,7,8 from buf0) ----
    ALOAD(6); MFMA_SH(0, 0);
    ALOAD(7); MFMA_SH(1, 0);
    ALOAD(8); MFMA_SH(2, 0);

#undef STAGE
#undef ALOAD
#undef MFMA_SH

    // ---- store (v3-verified): D col=frow(sp), cout row=(reg&3)+8*(reg>>2)+4*khalf ----
#pragma unroll
    for (int j = 0; j < 2; j++) {
        const int sp2 = spBase + wsp * 64 + j * 32 + frow;
        if (sp2 < SPTOT) {
            const int n2 = sp2 / OSP;
            const int r2 = sp2 - n2 * OSP;
            float* Ob = Out + (size_t)n2 * (COUT * (size_t)OSP) + r2;
#pragma unroll
            for (int i = 0; i < 2; i++) {
                const int cbase = wq2 * 64 + i * 32 + 4 * khalf;
#pragma unroll
                for (int reg = 0; reg < 16; reg++) {
                    const int crow = cbase + (reg & 3) + 8 * (reg >> 2);
                    Ob[(size_t)crow * OSP] = acc[i][j][reg];
                }
            }
        }
    }
}

extern "C" void kernel_launch(void* const* d_in, const int* in_sizes, int n_in,
                              void* d_out, int out_size, void* d_ws, size_t ws_size,
                              hipStream_t stream) {
    const float* X  = (const float*)d_in[0];
    const float* Kw = (const float*)d_in[1];
    float* Out = (float*)d_out;
    _Float16* A16  = (_Float16*)d_ws;
    _Float16* X16t = (_Float16*)((char*)d_ws + A16_BYTES);   // ~51.6 MB total ws

    prep_a<<<(COUT * KTOT + 255) / 256, 256, 0, stream>>>(Kw, A16);
    prep_x<<<NIMG * H, 256, 0, stream>>>(X, X16t);
    conv_v14<<<NWGM, 512, 0, stream>>>(X16t, A16, Out);
}